// Round 2
// baseline (839.916 us; speedup 1.0000x reference)
//
#include <hip/hip_runtime.h>
#include <stdint.h>

#define D 128
#define NROWS 300000
#define MIDX 262144
#define SBH 132                 // padded row stride (elements) for LDS transpose buffers
#define WAVE_BUF (16 * SBH)     // floats per wave buffer

typedef __attribute__((ext_vector_type(8))) short short8_t;
typedef __attribute__((ext_vector_type(4))) short short4_t;
typedef __attribute__((ext_vector_type(4))) float float4v;

__device__ __forceinline__ short f2bf(float x) {
  uint32_t u = __float_as_uint(x);
  u = (u + 0x7FFFu + ((u >> 16) & 1u)) >> 16;   // round-to-nearest-even
  return (short)u;
}

// ---------------- pass 1: last-write-wins winners ----------------
__global__ void winners_kernel(const int* __restrict__ idx_p,
                               const int* __restrict__ idx_k,
                               int* __restrict__ wp, int* __restrict__ wk) {
  int m = blockIdx.x * 256 + threadIdx.x;
  if (m < MIDX) {
    atomicMax(&wp[idx_p[m]], m);
    atomicMax(&wk[idx_k[m]], m);
  }
}

// ---------------- pass 1b: copy NON-winner rows straight through ----------------
// Winner rows (wp[i] >= 0) are written by fused_kernel's scatter; everything else
// is an identity passthrough of h_p/h_k.
__global__ __launch_bounds__(256)
void copyrest_kernel(const float* __restrict__ h_p, const float* __restrict__ h_k,
                     const int* __restrict__ wp, const int* __restrict__ wk,
                     float* __restrict__ out_p, float* __restrict__ out_k) {
  int g = blockIdx.x * 256 + threadIdx.x;
  int row = g >> 5;
  if (row >= NROWS) return;
  int c = (g & 31) << 2;
  size_t off = (size_t)row * D + c;
  if (wp[row] < 0) *(float4v*)(out_p + off) = *(const float4v*)(h_p + off);
  if (wk[row] < 0) *(float4v*)(out_k + off) = *(const float4v*)(h_k + off);
}

// ---------------- pass 2: pack weights into MFMA B-fragment layout ----------------
// B-frag for (tile t, kstep s): lane holds B[k=32s+8q+j][n=16t+l15], j=0..7,
// stored contiguously at ((t*4+s)*64+lane)*8  -> 16B coalesced loads in the GEMM.
// trans=1: B[k][n] = W[n][k]  (x @ W.T GEMMs, W is 128x128 row-major)
// trans=0: B[k][n] = W[k][n]  (x @ W GEMMs, W is 128x64 row-major)
__global__ void pack_kernel(const float* __restrict__ Wq, const float* __restrict__ Wk,
                            const float* __restrict__ Wv, const float* __restrict__ W1,
                            const float* __restrict__ Wl, const float* __restrict__ Wo,
                            const float* __restrict__ Wp, short* __restrict__ dst) {
  int slot = blockIdx.x;
  int lane = threadIdx.x;
  const float* W; int base; int trans; int rel;
  if      (slot < 32)  { W = Wq; base = 0;     trans = 1; rel = slot; }
  else if (slot < 64)  { W = Wk; base = 16384; trans = 1; rel = slot - 32; }
  else if (slot < 96)  { W = Wv; base = 32768; trans = 1; rel = slot - 64; }
  else if (slot < 128) { W = W1; base = 49152; trans = 1; rel = slot - 96; }
  else if (slot < 160) { W = Wl; base = 65536; trans = 1; rel = slot - 128; }
  else if (slot < 176) { W = Wo; base = 81920; trans = 0; rel = slot - 160; }
  else                 { W = Wp; base = 90112; trans = 0; rel = slot - 176; }
  int t = rel >> 2, s = rel & 3;
  int n = 16 * t + (lane & 15);
  int kb = 32 * s + 8 * (lane >> 4);
  short* o = dst + base + (size_t)(rel * 64 + lane) * 8;
  #pragma unroll
  for (int j = 0; j < 8; j++) {
    float v = trans ? W[n * 128 + kb + j] : W[(kb + j) * 64 + n];
    o[j] = f2bf(v);
  }
}

// ---------------- fused compute ----------------
__device__ __forceinline__ float4v gemm_tile(const short8_t a[4], const short* __restrict__ B,
                                             int t, int lane) {
  float4v acc = {0.f, 0.f, 0.f, 0.f};
  #pragma unroll
  for (int s = 0; s < 4; s++) {
    short8_t b = *(const short8_t*)(B + (size_t)((t * 4 + s) * 64 + lane) * 8);
    acc = __builtin_amdgcn_mfma_f32_16x16x32_bf16(a[s], b, acc, 0, 0, 0);
  }
  return acc;
}

// gather one 128-f32 row into A-operand bf16 fragments (m=l15, k=8q+32s+j)
__device__ __forceinline__ void load_row_frags(const float* __restrict__ row, int q, short8_t out[4]) {
  #pragma unroll
  for (int s = 0; s < 4; s++) {
    float4v v0 = *(const float4v*)(row + 32 * s + 8 * q);
    float4v v1 = *(const float4v*)(row + 32 * s + 8 * q + 4);
    short8_t r;
    r[0] = f2bf(v0[0]); r[1] = f2bf(v0[1]); r[2] = f2bf(v0[2]); r[3] = f2bf(v0[3]);
    r[4] = f2bf(v1[0]); r[5] = f2bf(v1[1]); r[6] = f2bf(v1[2]); r[7] = f2bf(v1[3]);
    out[s] = r;
  }
}

__device__ __forceinline__ void read_a_frags(const short* __restrict__ sb, int l15, int q, short8_t out[4]) {
  #pragma unroll
  for (int s = 0; s < 4; s++) {
    const short* p = sb + l15 * SBH + 32 * s + 8 * q;
    short4_t lo = *(const short4_t*)p;
    short4_t hi = *(const short4_t*)(p + 4);
    short8_t v;
    v[0] = lo[0]; v[1] = lo[1]; v[2] = lo[2]; v[3] = lo[3];
    v[4] = hi[0]; v[5] = hi[1]; v[6] = hi[2]; v[7] = hi[3];
    out[s] = v;
  }
}

__device__ __forceinline__ float red16(float v) {
  v += __shfl_xor(v, 1);
  v += __shfl_xor(v, 2);
  v += __shfl_xor(v, 4);
  v += __shfl_xor(v, 8);
  return v;
}

// ONE wave per workgroup: 8448B LDS/WG lets ~16-19 WGs pack per CU (vs 2x256-thread
// blocks at 33KB before -> ~8 waves/CU). Kernel is latency-bound with every pipe
// <25% busy; doubling resident waves is the concurrency lever.
__global__ __launch_bounds__(64, 4)
void fused_kernel(const float* __restrict__ h_p, const float* __restrict__ h_k,
                  const float* __restrict__ h_o, int ho_rows,
                  const int* __restrict__ idx_p, const int* __restrict__ idx_k,
                  const short* __restrict__ wbuf,
                  const float* __restrict__ bq, const float* __restrict__ bk,
                  const float* __restrict__ bv, const float* __restrict__ b1,
                  const float* __restrict__ linb, const float* __restrict__ bias,
                  const float* __restrict__ lng, const float* __restrict__ lnb,
                  const int* __restrict__ wp, const int* __restrict__ wk,
                  float* __restrict__ out_p, float* __restrict__ out_k)
{
  const short* Bq_ = wbuf;
  const short* Bk_ = wbuf + 16384;
  const short* Bv_ = wbuf + 32768;
  const short* B1_ = wbuf + 49152;
  const short* Bl_ = wbuf + 65536;
  const short* Bo_ = wbuf + 81920;
  const short* Bp_ = wbuf + 90112;

  __shared__ float smem[WAVE_BUF];
  const int lane = threadIdx.x & 63;
  const int l15  = lane & 15;
  const int q    = lane >> 4;

  float* fbuf = smem;
  short* sbuf = (short*)fbuf;

  const int m0   = blockIdx.x * 16;   // this wave's 16 rows
  const int mrow = m0 + l15;
  const int ip = idx_p[mrow];
  const int ik = idx_k[mrow];
  // JAX promise_in_bounds gather: out-of-bounds h_o indices CLAMP (idx in [0,N=300000)
  // but h_o has only ho_rows=262144 rows). Without this clamp we page-fault.
  const int ipo = (ip < ho_rows) ? ip : (ho_rows - 1);

  short8_t aho[4], ahp[4], ahk[4];
  load_row_frags(h_o + (size_t)ipo * D, q, aho);
  load_row_frags(h_p + (size_t)ip * D, q, ahp);
  load_row_frags(h_k + (size_t)ik * D, q, ahk);

  // ---- Q = ho_sel @ Wq.T + bq ----
  float4v Q[8];
  #pragma unroll
  for (int t = 0; t < 8; t++) {
    Q[t] = gemm_tile(aho, Bq_, t, lane) + bq[16 * t + l15];
  }

  // ---- logits s0,s1 (row-wise dot of Q with K0,K1) ----
  float4v p0 = {0,0,0,0}, p1 = {0,0,0,0};
  #pragma unroll
  for (int t = 0; t < 8; t++) {
    float bkv = bk[16 * t + l15];
    float4v k0 = gemm_tile(ahp, Bk_, t, lane) + bkv;
    float4v k1 = gemm_tile(ahk, Bk_, t, lane) + bkv;
    p0 += Q[t] * k0;
    p1 += Q[t] * k1;
  }
  float a0[4], a1[4];
  #pragma unroll
  for (int r = 0; r < 4; r++) {
    float s0 = red16(p0[r]) * 0.08838834764831845f;   // D^-0.5
    float s1 = red16(p1[r]) * 0.08838834764831845f;
    float mx = fmaxf(s0, s1);
    float e0 = __expf(s0 - mx), e1 = __expf(s1 - mx);
    float inv = 1.0f / (e0 + e1);
    a0[r] = e0 * inv;
    a1[r] = e1 * inv;
  }

  // ---- ctx = a0*V0 + a1*V1 ----
  float4v ctx[8];
  #pragma unroll
  for (int t = 0; t < 8; t++) {
    float bvv = bv[16 * t + l15];
    float4v v0 = gemm_tile(ahp, Bv_, t, lane) + bvv;
    float4v v1 = gemm_tile(ahk, Bv_, t, lane) + bvv;
    float4v c;
    #pragma unroll
    for (int r = 0; r < 4; r++) c[r] = a0[r] * v0[r] + a1[r] * v1[r];
    ctx[t] = c;
  }

  // ---- LDS round trip 1: ctx C-layout -> A-layout ----
  #pragma unroll
  for (int t = 0; t < 8; t++)
    #pragma unroll
    for (int r = 0; r < 4; r++)
      sbuf[(4 * q + r) * SBH + 16 * t + l15] = f2bf(ctx[t][r]);
  short8_t afu[4];
  read_a_frags(sbuf, l15, q, afu);

  // ---- fusion = ctx @ W1.T + b1, then LayerNorm ----
  float4v F[8];
  float4v sum = {0,0,0,0}, ssq = {0,0,0,0};
  #pragma unroll
  for (int t = 0; t < 8; t++) {
    float4v f = gemm_tile(afu, B1_, t, lane) + b1[16 * t + l15];
    F[t] = f;
    sum += f;
    ssq += f * f;
  }
  #pragma unroll
  for (int r = 0; r < 4; r++) {
    float s  = red16(sum[r]);
    float s2 = red16(ssq[r]);
    float mu  = s * (1.0f / 128.0f);
    float var = s2 * (1.0f / 128.0f) - mu * mu;
    float rs  = rsqrtf(var + 1e-5f);
    #pragma unroll
    for (int t = 0; t < 8; t++) F[t][r] = (F[t][r] - mu) * rs;
  }
  // apply gamma/beta, round trip 2
  #pragma unroll
  for (int t = 0; t < 8; t++) {
    int col = 16 * t + l15;
    float g = lng[col], b = lnb[col];
    #pragma unroll
    for (int r = 0; r < 4; r++)
      sbuf[(4 * q + r) * SBH + col] = f2bf(F[t][r] * g + b);
  }
  short8_t afn[4];
  read_a_frags(sbuf, l15, q, afn);

  // ---- u = tanh([ho_sel@weight_o , fusion@weight_p]) ----
  float4v U[8];
  #pragma unroll
  for (int t = 0; t < 4; t++) U[t]     = gemm_tile(aho, Bo_, t, lane);
  #pragma unroll
  for (int t = 0; t < 4; t++) U[4 + t] = gemm_tile(afn, Bp_, t, lane);
  #pragma unroll
  for (int t = 0; t < 8; t++) {
    #pragma unroll
    for (int r = 0; r < 4; r++) {
      float x  = U[t][r];
      float e  = __expf(-2.0f * fabsf(x));
      float th = (1.0f - e) / (1.0f + e);
      sbuf[(4 * q + r) * SBH + 16 * t + l15] = f2bf(copysignf(th, x));  // round trip 3
    }
  }
  short8_t au[4];
  read_a_frags(sbuf, l15, q, au);

  // ---- out = leaky_relu(u @ lin_W.T + lin_b) + bias  -> LDS fp32 ----
  #pragma unroll
  for (int t = 0; t < 8; t++) {
    int col = 16 * t + l15;
    float4v z = gemm_tile(au, Bl_, t, lane) + linb[col];
    float bb = bias[col];
    #pragma unroll
    for (int r = 0; r < 4; r++) {
      float x = z[r];
      x = (x > 0.0f) ? x : 0.01f * x;
      fbuf[(4 * q + r) * SBH + col] = x + bb;
    }
  }

  // ---- winner-checked scatter (4 lanes per row, 128B each) ----
  int r_out = lane >> 2;
  int cb    = (lane & 3) * 32;
  int mg    = m0 + r_out;
  int ip2 = idx_p[mg];
  int ik2 = idx_k[mg];
  bool dop = (wp[ip2] == mg);
  bool dok = (wk[ik2] == mg);
  const float* src = fbuf + r_out * SBH + cb;
  float* dp = out_p + (size_t)ip2 * D + cb;
  float* dk = out_k + (size_t)ik2 * D + cb;
  #pragma unroll
  for (int c = 0; c < 32; c += 4) {
    float4v v = *(const float4v*)(src + c);
    if (dop) *(float4v*)(dp + c) = v;
    if (dok) *(float4v*)(dk + c) = v;
  }
}

extern "C" void kernel_launch(void* const* d_in, const int* in_sizes, int n_in,
                              void* d_out, int out_size, void* d_ws, size_t ws_size,
                              hipStream_t stream) {
  const float* h_p      = (const float*)d_in[0];
  const float* h_k      = (const float*)d_in[1];
  const float* h_o      = (const float*)d_in[2];
  const float* weight_o = (const float*)d_in[3];
  const float* weight_p = (const float*)d_in[4];
  const float* lin_W    = (const float*)d_in[5];
  const float* lin_b    = (const float*)d_in[6];
  const float* bias     = (const float*)d_in[7];
  const float* Wq       = (const float*)d_in[8];
  const float* bq       = (const float*)d_in[9];
  const float* Wk       = (const float*)d_in[10];
  const float* bk       = (const float*)d_in[11];
  const float* Wv       = (const float*)d_in[12];
  const float* bv       = (const float*)d_in[13];
  const float* W1       = (const float*)d_in[14];
  const float* b1       = (const float*)d_in[15];
  const float* ln_g     = (const float*)d_in[16];
  const float* ln_b     = (const float*)d_in[17];
  const int*   idx_p    = (const int*)d_in[18];
  const int*   idx_k    = (const int*)d_in[19];

  const int ho_rows = in_sizes[2] / D;   // 262144 — NOT NROWS; indices must clamp

  float* out_p = (float*)d_out;
  float* out_k = out_p + (size_t)NROWS * D;

  int* wp = (int*)d_ws;
  int* wk = wp + NROWS;
  short* wbuf = (short*)((char*)d_ws + (size_t)2 * NROWS * 4);  // 2.4MB in, 16B aligned

  hipMemsetAsync(wp, 0xFF, (size_t)2 * NROWS * sizeof(int), stream);   // winners = -1

  winners_kernel<<<dim3(MIDX / 256), dim3(256), 0, stream>>>(idx_p, idx_k, wp, wk);
  // non-winner rows pass through h_p/h_k; winner rows are written by fused_kernel's scatter
  copyrest_kernel<<<dim3((NROWS * 32 + 255) / 256), dim3(256), 0, stream>>>(
      h_p, h_k, wp, wk, out_p, out_k);
  pack_kernel<<<dim3(192), dim3(64), 0, stream>>>(Wq, Wk, Wv, W1, lin_W, weight_o, weight_p, wbuf);
  fused_kernel<<<dim3(MIDX / 16), dim3(64), 0, stream>>>(
      h_p, h_k, h_o, ho_rows, idx_p, idx_k, wbuf, bq, bk, bv, b1, lin_b, bias, ln_g, ln_b,
      wp, wk, out_p, out_k);
}

// Round 3
// 763.006 us; speedup vs baseline: 1.1008x; 1.1008x over previous
//
#include <hip/hip_runtime.h>
#include <stdint.h>

#define D 128
#define NROWS 300000
#define MIDX 262144
#define SBH 132                 // padded row stride (elements) for LDS transpose buffers
#define WAVE_BUF (16 * SBH)     // floats per wave buffer

typedef __attribute__((ext_vector_type(8))) short short8_t;
typedef __attribute__((ext_vector_type(4))) short short4_t;
typedef __attribute__((ext_vector_type(4))) float float4v;

__device__ __forceinline__ short f2bf(float x) {
  uint32_t u = __float_as_uint(x);
  u = (u + 0x7FFFu + ((u >> 16) & 1u)) >> 16;   // round-to-nearest-even
  return (short)u;
}

// ---------------- pass 1: last-write-wins winners ----------------
__global__ void winners_kernel(const int* __restrict__ idx_p,
                               const int* __restrict__ idx_k,
                               int* __restrict__ wp, int* __restrict__ wk) {
  int m = blockIdx.x * 256 + threadIdx.x;
  if (m < MIDX) {
    atomicMax(&wp[idx_p[m]], m);
    atomicMax(&wk[idx_k[m]], m);
  }
}

// ---------------- pass 1b: copy NON-winner rows straight through ----------------
__global__ __launch_bounds__(256)
void copyrest_kernel(const float* __restrict__ h_p, const float* __restrict__ h_k,
                     const int* __restrict__ wp, const int* __restrict__ wk,
                     float* __restrict__ out_p, float* __restrict__ out_k) {
  int g = blockIdx.x * 256 + threadIdx.x;
  int row = g >> 5;
  if (row >= NROWS) return;
  int c = (g & 31) << 2;
  size_t off = (size_t)row * D + c;
  if (wp[row] < 0) *(float4v*)(out_p + off) = *(const float4v*)(h_p + off);
  if (wk[row] < 0) *(float4v*)(out_k + off) = *(const float4v*)(h_k + off);
}

// ---------------- pass 2: pack weights into MFMA B-fragment layout ----------------
// B-frag for (tile t, kstep s): lane holds B[k=32s+8q+j][n=16t+l15], j=0..7,
// stored contiguously at ((t*4+s)*64+lane)*8  -> 16B loads in the GEMM.
// trans=1: B[k][n] = W[n][k]  (x @ W.T GEMMs, W is 128x128 row-major)
// trans=0: B[k][n] = W[k][n]  (x @ W GEMMs, W is 128x64 row-major)
__global__ void pack_kernel(const float* __restrict__ Wq, const float* __restrict__ Wk,
                            const float* __restrict__ Wv, const float* __restrict__ W1,
                            const float* __restrict__ Wl, const float* __restrict__ Wo,
                            const float* __restrict__ Wp, short* __restrict__ dst) {
  int slot = blockIdx.x;
  int lane = threadIdx.x;
  const float* W; int base; int trans; int rel;
  if      (slot < 32)  { W = Wq; base = 0;     trans = 1; rel = slot; }
  else if (slot < 64)  { W = Wk; base = 16384; trans = 1; rel = slot - 32; }
  else if (slot < 96)  { W = Wv; base = 32768; trans = 1; rel = slot - 64; }
  else if (slot < 128) { W = W1; base = 49152; trans = 1; rel = slot - 96; }
  else if (slot < 160) { W = Wl; base = 65536; trans = 1; rel = slot - 128; }
  else if (slot < 176) { W = Wo; base = 81920; trans = 0; rel = slot - 160; }
  else                 { W = Wp; base = 90112; trans = 0; rel = slot - 176; }
  int t = rel >> 2, s = rel & 3;
  int n = 16 * t + (lane & 15);
  int kb = 32 * s + 8 * (lane >> 4);
  short* o = dst + base + (size_t)(rel * 64 + lane) * 8;
  #pragma unroll
  for (int j = 0; j < 8; j++) {
    float v = trans ? W[n * 128 + kb + j] : W[(kb + j) * 64 + n];
    o[j] = f2bf(v);
  }
}

// ---------------- fused compute ----------------
// B now read from LDS (staged once per WG per stage) instead of global: every wave
// previously streamed the same 180KB weight buffer through the L1-miss path (L1=32KB
// can't hold it) -> per-CU fixed-rate miss processing explained the occupancy-invariant
// ~300us. LDS staging cuts that traffic 5.5x and moves B reads to the LDS pipe.
__device__ __forceinline__ float4v gemm_tile_lds(const short8_t a[4], const short* B,
                                                 int t, int lane) {
  float4v acc = {0.f, 0.f, 0.f, 0.f};
  #pragma unroll
  for (int s = 0; s < 4; s++) {
    short8_t b = *(const short8_t*)(B + ((t * 4 + s) * 64 + lane) * 8);
    acc = __builtin_amdgcn_mfma_f32_16x16x32_bf16(a[s], b, acc, 0, 0, 0);
  }
  return acc;
}

// gather one 128-f32 row into A-operand bf16 fragments (m=l15, k=8q+32s+j)
__device__ __forceinline__ void load_row_frags(const float* __restrict__ row, int q, short8_t out[4]) {
  #pragma unroll
  for (int s = 0; s < 4; s++) {
    float4v v0 = *(const float4v*)(row + 32 * s + 8 * q);
    float4v v1 = *(const float4v*)(row + 32 * s + 8 * q + 4);
    short8_t r;
    r[0] = f2bf(v0[0]); r[1] = f2bf(v0[1]); r[2] = f2bf(v0[2]); r[3] = f2bf(v0[3]);
    r[4] = f2bf(v1[0]); r[5] = f2bf(v1[1]); r[6] = f2bf(v1[2]); r[7] = f2bf(v1[3]);
    out[s] = r;
  }
}

__device__ __forceinline__ void read_a_frags(const short* sb, int l15, int q, short8_t out[4]) {
  #pragma unroll
  for (int s = 0; s < 4; s++) {
    const short* p = sb + l15 * SBH + 32 * s + 8 * q;
    short4_t lo = *(const short4_t*)p;
    short4_t hi = *(const short4_t*)(p + 4);
    short8_t v;
    v[0] = lo[0]; v[1] = lo[1]; v[2] = lo[2]; v[3] = lo[3];
    v[4] = hi[0]; v[5] = hi[1]; v[6] = hi[2]; v[7] = hi[3];
    out[s] = v;
  }
}

__device__ __forceinline__ float red16(float v) {
  v += __shfl_xor(v, 1);
  v += __shfl_xor(v, 2);
  v += __shfl_xor(v, 4);
  v += __shfl_xor(v, 8);
  return v;
}

// LDS: 32KB B-stage buffer + 4x8448B transpose bufs = 65KB -> 2 WGs/CU.
// T14-style async staging: next stage's 32KB is loaded into registers BEFORE the
// current stage's compute (L2 latency hides under MFMA), written to LDS after the
// barrier that retires the previous stage's reads.
__global__ __launch_bounds__(256, 2)
void fused_kernel(const float* __restrict__ h_p, const float* __restrict__ h_k,
                  const float* __restrict__ h_o, int ho_rows,
                  const int* __restrict__ idx_p, const int* __restrict__ idx_k,
                  const short* __restrict__ wbuf,
                  const float* __restrict__ bq, const float* __restrict__ bk,
                  const float* __restrict__ bv, const float* __restrict__ b1,
                  const float* __restrict__ linb, const float* __restrict__ bias,
                  const float* __restrict__ lng, const float* __restrict__ lnb,
                  const int* __restrict__ wp, const int* __restrict__ wk,
                  float* __restrict__ out_p, float* __restrict__ out_k)
{
  const short* Bq_ = wbuf;            // 32KB each (Bo_/Bp_ are 16KB, contiguous)
  const short* Bk_ = wbuf + 16384;
  const short* Bv_ = wbuf + 32768;
  const short* B1_ = wbuf + 49152;
  const short* Bl_ = wbuf + 65536;
  const short* Bo_ = wbuf + 81920;    // Bp_ = Bo_ + 8192: staged together as one 32KB block

  __shared__ short bsh[16384];            // 32KB B stage buffer (shared by 4 waves)
  __shared__ float smem[4 * WAVE_BUF];    // per-wave transpose buffers

  const int tid  = threadIdx.x;
  const int wave = tid >> 6;
  const int lane = tid & 63;
  const int l15  = lane & 15;
  const int q    = lane >> 4;

  float* fbuf = smem + wave * WAVE_BUF;   // per-wave private, wave-coherent
  short* sbuf = (short*)fbuf;

  const int m0   = blockIdx.x * 64 + wave * 16;   // this wave's 16 rows
  const int mrow = m0 + l15;
  const int ip = idx_p[mrow];
  const int ik = idx_k[mrow];
  // JAX promise_in_bounds gather: h_o indices clamp (idx in [0,N) but h_o has ho_rows rows)
  const int ipo = (ip < ho_rows) ? ip : (ho_rows - 1);

  short8_t aho[4], ahp[4], ahk[4];
  load_row_frags(h_o + (size_t)ipo * D, q, aho);
  load_row_frags(h_p + (size_t)ip * D, q, ahp);
  load_row_frags(h_k + (size_t)ik * D, q, ahk);

  short8_t breg[8];   // in-flight next-stage block: 128B/thread, 256 threads = 32KB

  #define LDSTAGE(SRC) { _Pragma("unroll") \
    for (int r_ = 0; r_ < 8; r_++) breg[r_] = *(const short8_t*)((SRC) + (r_ * 256 + tid) * 8); }
  #define STSTAGE() { _Pragma("unroll") \
    for (int r_ = 0; r_ < 8; r_++) *(short8_t*)(bsh + (r_ * 256 + tid) * 8) = breg[r_]; }

  // prologue: Bq -> regs -> LDS; prefetch Bk
  LDSTAGE(Bq_);
  STSTAGE();
  LDSTAGE(Bk_);
  __syncthreads();                 // Bq visible

  // ---- Q = ho_sel @ Wq.T + bq ----
  float4v Q[8];
  #pragma unroll
  for (int t = 0; t < 8; t++) {
    Q[t] = gemm_tile_lds(aho, bsh, t, lane) + bq[16 * t + l15];
  }

  __syncthreads();                 // Bq reads retired
  STSTAGE();                       // Bk -> LDS
  LDSTAGE(Bv_);                    // prefetch Bv
  __syncthreads();                 // Bk visible

  // ---- logits s0,s1 (row-wise dot of Q with K0,K1) ----
  float4v p0 = {0,0,0,0}, p1 = {0,0,0,0};
  #pragma unroll
  for (int t = 0; t < 8; t++) {
    float bkv = bk[16 * t + l15];
    float4v k0 = gemm_tile_lds(ahp, bsh, t, lane) + bkv;
    float4v k1 = gemm_tile_lds(ahk, bsh, t, lane) + bkv;
    p0 += Q[t] * k0;
    p1 += Q[t] * k1;
  }
  float a0[4], a1[4];
  #pragma unroll
  for (int r = 0; r < 4; r++) {
    float s0 = red16(p0[r]) * 0.08838834764831845f;   // D^-0.5
    float s1 = red16(p1[r]) * 0.08838834764831845f;
    float mx = fmaxf(s0, s1);
    float e0 = __expf(s0 - mx), e1 = __expf(s1 - mx);
    float inv = 1.0f / (e0 + e1);
    a0[r] = e0 * inv;
    a1[r] = e1 * inv;
  }

  __syncthreads();
  STSTAGE();                       // Bv -> LDS
  LDSTAGE(B1_);
  __syncthreads();

  // ---- ctx = a0*V0 + a1*V1 ----
  float4v ctx[8];
  #pragma unroll
  for (int t = 0; t < 8; t++) {
    float bvv = bv[16 * t + l15];
    float4v v0 = gemm_tile_lds(ahp, bsh, t, lane) + bvv;
    float4v v1 = gemm_tile_lds(ahk, bsh, t, lane) + bvv;
    float4v c;
    #pragma unroll
    for (int r = 0; r < 4; r++) c[r] = a0[r] * v0[r] + a1[r] * v1[r];
    ctx[t] = c;
  }

  // ---- LDS round trip 1: ctx C-layout -> A-layout (per-wave private buffer) ----
  #pragma unroll
  for (int t = 0; t < 8; t++)
    #pragma unroll
    for (int r = 0; r < 4; r++)
      sbuf[(4 * q + r) * SBH + 16 * t + l15] = f2bf(ctx[t][r]);
  short8_t afu[4];
  read_a_frags(sbuf, l15, q, afu);

  __syncthreads();
  STSTAGE();                       // B1 -> LDS
  LDSTAGE(Bo_);                    // prefetch Bo|Bp (16KB+16KB contiguous)
  __syncthreads();

  // ---- fusion = ctx @ W1.T + b1, then LayerNorm ----
  float4v F[8];
  float4v sum = {0,0,0,0}, ssq = {0,0,0,0};
  #pragma unroll
  for (int t = 0; t < 8; t++) {
    float4v f = gemm_tile_lds(afu, bsh, t, lane) + b1[16 * t + l15];
    F[t] = f;
    sum += f;
    ssq += f * f;
  }
  #pragma unroll
  for (int r = 0; r < 4; r++) {
    float s  = red16(sum[r]);
    float s2 = red16(ssq[r]);
    float mu  = s * (1.0f / 128.0f);
    float var = s2 * (1.0f / 128.0f) - mu * mu;
    float rs  = rsqrtf(var + 1e-5f);
    #pragma unroll
    for (int t = 0; t < 8; t++) F[t][r] = (F[t][r] - mu) * rs;
  }
  // apply gamma/beta, round trip 2
  #pragma unroll
  for (int t = 0; t < 8; t++) {
    int col = 16 * t + l15;
    float g = lng[col], b = lnb[col];
    #pragma unroll
    for (int r = 0; r < 4; r++)
      sbuf[(4 * q + r) * SBH + col] = f2bf(F[t][r] * g + b);
  }
  short8_t afn[4];
  read_a_frags(sbuf, l15, q, afn);

  __syncthreads();
  STSTAGE();                       // Bo|Bp -> LDS
  LDSTAGE(Bl_);
  __syncthreads();

  // ---- u = tanh([ho_sel@weight_o , fusion@weight_p]) ----
  float4v U[8];
  #pragma unroll
  for (int t = 0; t < 4; t++) U[t]     = gemm_tile_lds(aho, bsh, t, lane);
  #pragma unroll
  for (int t = 0; t < 4; t++) U[4 + t] = gemm_tile_lds(afn, bsh + 8192, t, lane);
  #pragma unroll
  for (int t = 0; t < 8; t++) {
    #pragma unroll
    for (int r = 0; r < 4; r++) {
      float x  = U[t][r];
      float e  = __expf(-2.0f * fabsf(x));
      float th = (1.0f - e) / (1.0f + e);
      sbuf[(4 * q + r) * SBH + 16 * t + l15] = f2bf(copysignf(th, x));  // round trip 3
    }
  }
  short8_t au[4];
  read_a_frags(sbuf, l15, q, au);

  __syncthreads();
  STSTAGE();                       // Bl -> LDS
  __syncthreads();

  // ---- out = leaky_relu(u @ lin_W.T + lin_b) + bias  -> LDS fp32 ----
  #pragma unroll
  for (int t = 0; t < 8; t++) {
    int col = 16 * t + l15;
    float4v z = gemm_tile_lds(au, bsh, t, lane) + linb[col];
    float bb = bias[col];
    #pragma unroll
    for (int r = 0; r < 4; r++) {
      float x = z[r];
      x = (x > 0.0f) ? x : 0.01f * x;
      fbuf[(4 * q + r) * SBH + col] = x + bb;
    }
  }

  // ---- winner-checked scatter (4 lanes per row, 128B each) ----
  int r_out = lane >> 2;
  int cb    = (lane & 3) * 32;
  int mg    = m0 + r_out;
  int ip2 = idx_p[mg];
  int ik2 = idx_k[mg];
  bool dop = (wp[ip2] == mg);
  bool dok = (wk[ik2] == mg);
  const float* src = fbuf + r_out * SBH + cb;
  float* dp = out_p + (size_t)ip2 * D + cb;
  float* dk = out_k + (size_t)ik2 * D + cb;
  #pragma unroll
  for (int c = 0; c < 32; c += 4) {
    float4v v = *(const float4v*)(src + c);
    if (dop) *(float4v*)(dp + c) = v;
    if (dok) *(float4v*)(dk + c) = v;
  }
  #undef LDSTAGE
  #undef STSTAGE
}

extern "C" void kernel_launch(void* const* d_in, const int* in_sizes, int n_in,
                              void* d_out, int out_size, void* d_ws, size_t ws_size,
                              hipStream_t stream) {
  const float* h_p      = (const float*)d_in[0];
  const float* h_k      = (const float*)d_in[1];
  const float* h_o      = (const float*)d_in[2];
  const float* weight_o = (const float*)d_in[3];
  const float* weight_p = (const float*)d_in[4];
  const float* lin_W    = (const float*)d_in[5];
  const float* lin_b    = (const float*)d_in[6];
  const float* bias     = (const float*)d_in[7];
  const float* Wq       = (const float*)d_in[8];
  const float* bq       = (const float*)d_in[9];
  const float* Wk       = (const float*)d_in[10];
  const float* bk       = (const float*)d_in[11];
  const float* Wv       = (const float*)d_in[12];
  const float* bv       = (const float*)d_in[13];
  const float* W1       = (const float*)d_in[14];
  const float* b1       = (const float*)d_in[15];
  const float* ln_g     = (const float*)d_in[16];
  const float* ln_b     = (const float*)d_in[17];
  const int*   idx_p    = (const int*)d_in[18];
  const int*   idx_k    = (const int*)d_in[19];

  const int ho_rows = in_sizes[2] / D;   // 262144 — NOT NROWS; indices must clamp

  float* out_p = (float*)d_out;
  float* out_k = out_p + (size_t)NROWS * D;

  int* wp = (int*)d_ws;
  int* wk = wp + NROWS;
  short* wbuf = (short*)((char*)d_ws + (size_t)2 * NROWS * 4);  // 2.4MB in, 16B aligned

  hipMemsetAsync(wp, 0xFF, (size_t)2 * NROWS * sizeof(int), stream);   // winners = -1

  winners_kernel<<<dim3(MIDX / 256), dim3(256), 0, stream>>>(idx_p, idx_k, wp, wk);
  // non-winner rows pass through h_p/h_k; winner rows are written by fused_kernel's scatter
  copyrest_kernel<<<dim3((NROWS * 32 + 255) / 256), dim3(256), 0, stream>>>(
      h_p, h_k, wp, wk, out_p, out_k);
  pack_kernel<<<dim3(192), dim3(64), 0, stream>>>(Wq, Wk, Wv, W1, lin_W, weight_o, weight_p, wbuf);
  fused_kernel<<<dim3(MIDX / 64), dim3(256), 0, stream>>>(
      h_p, h_k, h_o, ho_rows, idx_p, idx_k, wbuf, bq, bk, bv, b1, lin_b, bias, ln_g, ln_b,
      wp, wk, out_p, out_k);
}

// Round 4
// 750.910 us; speedup vs baseline: 1.1185x; 1.0161x over previous
//
#include <hip/hip_runtime.h>
#include <stdint.h>

#define D 128
#define NROWS 300000
#define MIDX 262144
#define SBH 132                 // padded row stride (elements) for LDS transpose buffers
#define WBUF_SH (32 * SBH)      // shorts per wave transpose buffer (32 bf16 rows = 8448 B)

typedef __attribute__((ext_vector_type(8))) short short8_t;
typedef __attribute__((ext_vector_type(4))) short short4_t;
typedef __attribute__((ext_vector_type(4))) float float4v;

__device__ __forceinline__ short f2bf(float x) {
  uint32_t u = __float_as_uint(x);
  u = (u + 0x7FFFu + ((u >> 16) & 1u)) >> 16;   // round-to-nearest-even
  return (short)u;
}
__device__ __forceinline__ float bf2f(short s) {
  return __uint_as_float(((uint32_t)(uint16_t)s) << 16);
}

// ---------------- pass 1: last-write-wins winners ----------------
__global__ void winners_kernel(const int* __restrict__ idx_p,
                               const int* __restrict__ idx_k,
                               int* __restrict__ wp, int* __restrict__ wk) {
  int m = blockIdx.x * 256 + threadIdx.x;
  if (m < MIDX) {
    atomicMax(&wp[idx_p[m]], m);
    atomicMax(&wk[idx_k[m]], m);
  }
}

// ---------------- pass 1b: copy NON-winner rows straight through ----------------
__global__ __launch_bounds__(256)
void copyrest_kernel(const float* __restrict__ h_p, const float* __restrict__ h_k,
                     const int* __restrict__ wp, const int* __restrict__ wk,
                     float* __restrict__ out_p, float* __restrict__ out_k) {
  int g = blockIdx.x * 256 + threadIdx.x;
  int row = g >> 5;
  if (row >= NROWS) return;
  int c = (g & 31) << 2;
  size_t off = (size_t)row * D + c;
  if (wp[row] < 0) *(float4v*)(out_p + off) = *(const float4v*)(h_p + off);
  if (wk[row] < 0) *(float4v*)(out_k + off) = *(const float4v*)(h_k + off);
}

// ---------------- pass 1c: M = Wq^T @ Wk, v2 = Wk^T @ bq ----------------
// Softmax logit folding: Q.K = x_o^T (Wq^T Wk) x + (terms constant over the 2 keys,
// which cancel in softmax) + x.(Wk^T bq).  So s_eff = (x_o @ M + v2) . x.
// This deletes the Q and K GEMM stages of the fused kernel (3 GEMM-units -> 1).
__global__ void prep_m_kernel(const float* __restrict__ Wq, const float* __restrict__ Wk,
                              const float* __restrict__ bq,
                              float* __restrict__ Mbuf, float* __restrict__ v2) {
  int b = blockIdx.x;
  if (b < 64) {                       // 16x16 tile of M per block
    int d = ((b >> 3) << 4) + (threadIdx.x >> 4);
    int e = ((b & 7) << 4) + (threadIdx.x & 15);
    float acc = 0.f;
    for (int j = 0; j < 128; j++) acc += Wq[j * 128 + d] * Wk[j * 128 + e];
    Mbuf[d * 128 + e] = acc;
  } else if (threadIdx.x < 128) {
    int e = threadIdx.x;
    float acc = 0.f;
    for (int j = 0; j < 128; j++) acc += bq[j] * Wk[j * 128 + e];
    v2[e] = acc;
  }
}

// ---------------- pass 2: pack weights into MFMA B-fragment layout ----------------
// B-frag for (tile t, kstep s): lane holds B[k=32s+8q+j][n=16t+l15], j=0..7,
// stored contiguously at ((t*4+s)*64+lane)*8  -> 16B loads in the GEMM.
// trans=1: B[k][n] = W[n][k]  (x @ W.T GEMMs, W is 128x128 row-major)
// trans=0: B[k][n] = W[k][n]  (x @ W GEMMs, W row-major, row width wdt)
// Layout (shorts): Bm 0 | Bv 16384 | B1 32768 | Bo 49152 | Bp 57344 | Bl 65536
__global__ void pack_kernel(const float* __restrict__ Mb, const float* __restrict__ Wv,
                            const float* __restrict__ W1, const float* __restrict__ Wl,
                            const float* __restrict__ Wo, const float* __restrict__ Wp,
                            short* __restrict__ dst) {
  int slot = blockIdx.x;
  int lane = threadIdx.x;
  const float* W; int base; int trans; int rel; int wdt = 128;
  if      (slot < 32)  { W = Mb; base = 0;     trans = 0; rel = slot; }
  else if (slot < 64)  { W = Wv; base = 16384; trans = 1; rel = slot - 32; }
  else if (slot < 96)  { W = W1; base = 32768; trans = 1; rel = slot - 64; }
  else if (slot < 112) { W = Wo; base = 49152; trans = 0; rel = slot - 96;  wdt = 64; }
  else if (slot < 128) { W = Wp; base = 57344; trans = 0; rel = slot - 112; wdt = 64; }
  else                 { W = Wl; base = 65536; trans = 1; rel = slot - 128; }
  int t = rel >> 2, s = rel & 3;
  int n = 16 * t + (lane & 15);
  int kb = 32 * s + 8 * (lane >> 4);
  short* o = dst + base + (size_t)(rel * 64 + lane) * 8;
  #pragma unroll
  for (int j = 0; j < 8; j++) {
    float v = trans ? W[n * 128 + kb + j] : W[(kb + j) * wdt + n];
    o[j] = f2bf(v);
  }
}

// ---------------- fused compute ----------------
// One b-frag read feeds 2 (or 4) MFMAs: each wave owns TWO 16-row tiles (32 rows),
// halving B ds_read + staging L2 traffic + barriers per row and doubling MFMA ILP.
__device__ __forceinline__ void gemm2(const short8_t a0[4], const short8_t a1[4],
                                      const short* B, int t, int lane,
                                      float4v& c0, float4v& c1) {
  #pragma unroll
  for (int s = 0; s < 4; s++) {
    short8_t b = *(const short8_t*)(B + ((t * 4 + s) * 64 + lane) * 8);
    c0 = __builtin_amdgcn_mfma_f32_16x16x32_bf16(a0[s], b, c0, 0, 0, 0);
    c1 = __builtin_amdgcn_mfma_f32_16x16x32_bf16(a1[s], b, c1, 0, 0, 0);
  }
}
__device__ __forceinline__ void gemm4(const short8_t a0[4], const short8_t a1[4],
                                      const short8_t a2[4], const short8_t a3[4],
                                      const short* B, int t, int lane,
                                      float4v& c0, float4v& c1, float4v& c2, float4v& c3) {
  #pragma unroll
  for (int s = 0; s < 4; s++) {
    short8_t b = *(const short8_t*)(B + ((t * 4 + s) * 64 + lane) * 8);
    c0 = __builtin_amdgcn_mfma_f32_16x16x32_bf16(a0[s], b, c0, 0, 0, 0);
    c1 = __builtin_amdgcn_mfma_f32_16x16x32_bf16(a1[s], b, c1, 0, 0, 0);
    c2 = __builtin_amdgcn_mfma_f32_16x16x32_bf16(a2[s], b, c2, 0, 0, 0);
    c3 = __builtin_amdgcn_mfma_f32_16x16x32_bf16(a3[s], b, c3, 0, 0, 0);
  }
}

// gather one 128-f32 row into A-operand bf16 fragments (m=l15, k=8q+32s+j)
__device__ __forceinline__ void load_row_frags(const float* __restrict__ row, int q, short8_t out[4]) {
  #pragma unroll
  for (int s = 0; s < 4; s++) {
    float4v v0 = *(const float4v*)(row + 32 * s + 8 * q);
    float4v v1 = *(const float4v*)(row + 32 * s + 8 * q + 4);
    short8_t r;
    r[0] = f2bf(v0[0]); r[1] = f2bf(v0[1]); r[2] = f2bf(v0[2]); r[3] = f2bf(v0[3]);
    r[4] = f2bf(v1[0]); r[5] = f2bf(v1[1]); r[6] = f2bf(v1[2]); r[7] = f2bf(v1[3]);
    out[s] = r;
  }
}

__device__ __forceinline__ void read_a_frags(const short* sb, int row, int q, short8_t out[4]) {
  #pragma unroll
  for (int s = 0; s < 4; s++) {
    const short* p = sb + row * SBH + 32 * s + 8 * q;
    short4_t lo = *(const short4_t*)p;
    short4_t hi = *(const short4_t*)(p + 4);
    short8_t v;
    v[0] = lo[0]; v[1] = lo[1]; v[2] = lo[2]; v[3] = lo[3];
    v[4] = hi[0]; v[5] = hi[1]; v[6] = hi[2]; v[7] = hi[3];
    out[s] = v;
  }
}

__device__ __forceinline__ float red16(float v) {
  v += __shfl_xor(v, 1);
  v += __shfl_xor(v, 2);
  v += __shfl_xor(v, 4);
  v += __shfl_xor(v, 8);
  return v;
}

// LDS: 32KB B-stage + 4x8448B transpose bufs = 65KB -> 2 WGs/CU (8 waves, 2/SIMD).
// Stage pipeline (T14): next stage's 32KB loaded to regs before compute, written
// to LDS after the retire barrier.
__global__ __launch_bounds__(256, 2)
void fused_kernel(const float* __restrict__ h_p, const float* __restrict__ h_k,
                  const float* __restrict__ h_o, int ho_rows,
                  const int* __restrict__ idx_p, const int* __restrict__ idx_k,
                  const short* __restrict__ wbuf, const float* __restrict__ v2,
                  const float* __restrict__ bv, const float* __restrict__ b1,
                  const float* __restrict__ linb, const float* __restrict__ bias,
                  const float* __restrict__ lng, const float* __restrict__ lnb,
                  const int* __restrict__ wp, const int* __restrict__ wk,
                  float* __restrict__ out_p, float* __restrict__ out_k)
{
  const short* Bm_  = wbuf;
  const short* Bv_  = wbuf + 16384;
  const short* B1_  = wbuf + 32768;
  const short* Bop_ = wbuf + 49152;   // Bo (8192) | Bp (8192), staged as one 32KB block
  const short* Bl_  = wbuf + 65536;

  __shared__ short bsh[16384];             // 32KB B stage buffer (shared by 4 waves)
  __shared__ short tmem[4 * WBUF_SH];      // per-wave transpose buffers

  const int tid  = threadIdx.x;
  const int wave = tid >> 6;
  const int lane = tid & 63;
  const int l15  = lane & 15;
  const int q    = lane >> 4;

  short* sbuf = tmem + wave * WBUF_SH;     // per-wave private, wave-coherent
  float* fbuf = (float*)sbuf;              // 16 rows fp32 view for the final scatter

  const int m0  = blockIdx.x * 128 + wave * 32;  // this wave's 32 rows (2 tiles)
  const int mr0 = m0 + l15;
  const int mr1 = m0 + 16 + l15;
  const int ip0 = idx_p[mr0], ik0 = idx_k[mr0];
  const int ip1 = idx_p[mr1], ik1 = idx_k[mr1];
  // JAX promise_in_bounds gather: h_o indices clamp (idx in [0,N) but h_o has ho_rows rows)
  const int ipo0 = (ip0 < ho_rows) ? ip0 : (ho_rows - 1);
  const int ipo1 = (ip1 < ho_rows) ? ip1 : (ho_rows - 1);

  short8_t aho0[4], ahp0[4], ahk0[4], aho1[4], ahp1[4], ahk1[4];
  load_row_frags(h_o + (size_t)ipo0 * D, q, aho0);
  load_row_frags(h_p + (size_t)ip0 * D, q, ahp0);
  load_row_frags(h_k + (size_t)ik0 * D, q, ahk0);
  load_row_frags(h_o + (size_t)ipo1 * D, q, aho1);
  load_row_frags(h_p + (size_t)ip1 * D, q, ahp1);
  load_row_frags(h_k + (size_t)ik1 * D, q, ahk1);

  short8_t breg[8];   // in-flight next-stage block: 128B/thread x 256 threads = 32KB

  #define LDSTAGE(SRC) { _Pragma("unroll") \
    for (int r_ = 0; r_ < 8; r_++) breg[r_] = *(const short8_t*)((SRC) + (r_ * 256 + tid) * 8); }
  #define STSTAGE() { _Pragma("unroll") \
    for (int r_ = 0; r_ < 8; r_++) *(short8_t*)(bsh + (r_ * 256 + tid) * 8) = breg[r_]; }

  LDSTAGE(Bm_);
  STSTAGE();
  LDSTAGE(Bv_);
  __syncthreads();                 // Bm visible

  // ---- S1: g = x_o @ M + v2; logits via in-register bf16 dots; softmax ----
  #pragma unroll
  for (int t = 0; t < 8; t++) {
    float4v g0 = {0,0,0,0}, g1 = {0,0,0,0};
    gemm2(aho0, aho1, bsh, t, lane, g0, g1);
    float vv = v2[16 * t + l15];
    #pragma unroll
    for (int r = 0; r < 4; r++) {
      sbuf[(4 * q + r) * SBH + 16 * t + l15]        = f2bf(g0[r] + vv);
      sbuf[(16 + 4 * q + r) * SBH + 16 * t + l15]   = f2bf(g1[r] + vv);
    }
  }
  short8_t afg0[4], afg1[4];
  read_a_frags(sbuf, l15, q, afg0);
  read_a_frags(sbuf, 16 + l15, q, afg1);

  float e00 = 0.f, e01 = 0.f, e10 = 0.f, e11 = 0.f;   // [tile][key]
  #pragma unroll
  for (int s = 0; s < 4; s++)
    #pragma unroll
    for (int j = 0; j < 8; j++) {
      float ga = bf2f(afg0[s][j]);
      float gb = bf2f(afg1[s][j]);
      e00 += ga * bf2f(ahp0[s][j]);
      e01 += ga * bf2f(ahk0[s][j]);
      e10 += gb * bf2f(ahp1[s][j]);
      e11 += gb * bf2f(ahk1[s][j]);
    }
  e00 += __shfl_xor(e00, 16); e00 += __shfl_xor(e00, 32);   // reduce over q-groups
  e01 += __shfl_xor(e01, 16); e01 += __shfl_xor(e01, 32);
  e10 += __shfl_xor(e10, 16); e10 += __shfl_xor(e10, 32);
  e11 += __shfl_xor(e11, 16); e11 += __shfl_xor(e11, 32);
  const float sc = 0.08838834764831845f;                    // D^-0.5
  float s00 = e00 * sc, s01 = e01 * sc, s10 = e10 * sc, s11 = e11 * sc;
  float mx0 = fmaxf(s00, s01), mx1 = fmaxf(s10, s11);
  float x00 = __expf(s00 - mx0), x01 = __expf(s01 - mx0);
  float x10 = __expf(s10 - mx1), x11 = __expf(s11 - mx1);
  float i0 = 1.0f / (x00 + x01), i1 = 1.0f / (x10 + x11);
  float w00 = x00 * i0, w01 = x01 * i0, w10 = x10 * i1, w11 = x11 * i1;
  // redistribute row-indexed weights (at lane l15=row) to C-layout rows 4q+r
  float a00[4], a01[4], a10[4], a11[4];
  #pragma unroll
  for (int r = 0; r < 4; r++) {
    int src = 4 * q + r;
    a00[r] = __shfl(w00, src);
    a01[r] = __shfl(w01, src);
    a10[r] = __shfl(w10, src);
    a11[r] = __shfl(w11, src);
  }

  __syncthreads();                 // Bm reads retired
  STSTAGE();                       // Bv -> LDS
  LDSTAGE(B1_);
  __syncthreads();                 // Bv visible

  // ---- S2: ctx = a0*V0 + a1*V1 (4 GEMMs share each b-frag) ----
  #pragma unroll
  for (int t = 0; t < 8; t++) {
    float4v vp0 = {0,0,0,0}, vk0 = {0,0,0,0}, vp1 = {0,0,0,0}, vk1 = {0,0,0,0};
    gemm4(ahp0, ahk0, ahp1, ahk1, bsh, t, lane, vp0, vk0, vp1, vk1);
    float bvv = bv[16 * t + l15];
    #pragma unroll
    for (int r = 0; r < 4; r++) {
      float c0 = a00[r] * (vp0[r] + bvv) + a01[r] * (vk0[r] + bvv);
      float c1 = a10[r] * (vp1[r] + bvv) + a11[r] * (vk1[r] + bvv);
      sbuf[(4 * q + r) * SBH + 16 * t + l15]      = f2bf(c0);
      sbuf[(16 + 4 * q + r) * SBH + 16 * t + l15] = f2bf(c1);
    }
  }
  short8_t afu0[4], afu1[4];
  read_a_frags(sbuf, l15, q, afu0);
  read_a_frags(sbuf, 16 + l15, q, afu1);

  __syncthreads();
  STSTAGE();                       // B1 -> LDS
  LDSTAGE(Bop_);
  __syncthreads();

  // ---- S3: fusion = ctx @ W1.T + b1, LayerNorm ----
  float4v F0[8], F1[8];
  float4v sum0 = {0,0,0,0}, ssq0 = {0,0,0,0}, sum1 = {0,0,0,0}, ssq1 = {0,0,0,0};
  #pragma unroll
  for (int t = 0; t < 8; t++) {
    float4v f0 = {0,0,0,0}, f1 = {0,0,0,0};
    gemm2(afu0, afu1, bsh, t, lane, f0, f1);
    float bb = b1[16 * t + l15];
    f0 = f0 + bb; f1 = f1 + bb;
    F0[t] = f0; F1[t] = f1;
    sum0 += f0; ssq0 += f0 * f0;
    sum1 += f1; ssq1 += f1 * f1;
  }
  float mu0[4], rs0[4], mu1[4], rs1[4];
  #pragma unroll
  for (int r = 0; r < 4; r++) {
    float s  = red16(sum0[r]);
    float s2 = red16(ssq0[r]);
    float m  = s * (1.0f / 128.0f);
    mu0[r] = m;
    rs0[r] = rsqrtf(s2 * (1.0f / 128.0f) - m * m + 1e-5f);
    s  = red16(sum1[r]);
    s2 = red16(ssq1[r]);
    m  = s * (1.0f / 128.0f);
    mu1[r] = m;
    rs1[r] = rsqrtf(s2 * (1.0f / 128.0f) - m * m + 1e-5f);
  }
  #pragma unroll
  for (int t = 0; t < 8; t++) {
    int col = 16 * t + l15;
    float g = lng[col], b = lnb[col];
    #pragma unroll
    for (int r = 0; r < 4; r++) {
      sbuf[(4 * q + r) * SBH + col]      = f2bf((F0[t][r] - mu0[r]) * rs0[r] * g + b);
      sbuf[(16 + 4 * q + r) * SBH + col] = f2bf((F1[t][r] - mu1[r]) * rs1[r] * g + b);
    }
  }
  short8_t afn0[4], afn1[4];
  read_a_frags(sbuf, l15, q, afn0);
  read_a_frags(sbuf, 16 + l15, q, afn1);

  __syncthreads();
  STSTAGE();                       // Bo|Bp -> LDS
  LDSTAGE(Bl_);
  __syncthreads();

  // ---- S4: u = tanh([ho_sel@weight_o , fusion@weight_p]) ----
  #pragma unroll
  for (int t = 0; t < 4; t++) {
    float4v u0 = {0,0,0,0}, u1 = {0,0,0,0};
    gemm2(aho0, aho1, bsh, t, lane, u0, u1);
    #pragma unroll
    for (int r = 0; r < 4; r++) {
      float xa = u0[r], ea = __expf(-2.0f * fabsf(xa));
      float xb = u1[r], eb = __expf(-2.0f * fabsf(xb));
      sbuf[(4 * q + r) * SBH + 16 * t + l15]      = f2bf(copysignf((1.0f - ea) / (1.0f + ea), xa));
      sbuf[(16 + 4 * q + r) * SBH + 16 * t + l15] = f2bf(copysignf((1.0f - eb) / (1.0f + eb), xb));
    }
  }
  #pragma unroll
  for (int t = 0; t < 4; t++) {
    float4v u0 = {0,0,0,0}, u1 = {0,0,0,0};
    gemm2(afn0, afn1, bsh + 8192, t, lane, u0, u1);
    #pragma unroll
    for (int r = 0; r < 4; r++) {
      float xa = u0[r], ea = __expf(-2.0f * fabsf(xa));
      float xb = u1[r], eb = __expf(-2.0f * fabsf(xb));
      sbuf[(4 * q + r) * SBH + 64 + 16 * t + l15]      = f2bf(copysignf((1.0f - ea) / (1.0f + ea), xa));
      sbuf[(16 + 4 * q + r) * SBH + 64 + 16 * t + l15] = f2bf(copysignf((1.0f - eb) / (1.0f + eb), xb));
    }
  }
  short8_t au0[4], au1[4];
  read_a_frags(sbuf, l15, q, au0);
  read_a_frags(sbuf, 16 + l15, q, au1);

  __syncthreads();
  STSTAGE();                       // Bl -> LDS
  __syncthreads();

  // ---- S5: out = leaky_relu(u @ lin_W.T + lin_b) + bias, two 16-row scatter passes ----
  float4v z0[8], z1[8];
  #pragma unroll
  for (int t = 0; t < 8; t++) {
    float4v c0 = {0,0,0,0}, c1 = {0,0,0,0};
    gemm2(au0, au1, bsh, t, lane, c0, c1);
    float lb = linb[16 * t + l15];
    z0[t] = c0 + lb;
    z1[t] = c1 + lb;
  }
  // pass 0 (rows m0..m0+15)
  #pragma unroll
  for (int t = 0; t < 8; t++) {
    int col = 16 * t + l15;
    float bb = bias[col];
    #pragma unroll
    for (int r = 0; r < 4; r++) {
      float x = z0[t][r];
      x = (x > 0.0f) ? x : 0.01f * x;
      fbuf[(4 * q + r) * SBH + col] = x + bb;
    }
  }
  {
    int r_out = lane >> 2, cb = (lane & 3) * 32, mg = m0 + r_out;
    int ip2 = idx_p[mg], ik2 = idx_k[mg];
    bool dop = (wp[ip2] == mg), dok = (wk[ik2] == mg);
    const float* src = fbuf + r_out * SBH + cb;
    float* dp = out_p + (size_t)ip2 * D + cb;
    float* dk = out_k + (size_t)ik2 * D + cb;
    #pragma unroll
    for (int c = 0; c < 32; c += 4) {
      float4v v = *(const float4v*)(src + c);
      if (dop) *(float4v*)(dp + c) = v;
      if (dok) *(float4v*)(dk + c) = v;
    }
  }
  // pass 1 (rows m0+16..m0+31) — same wave, LDS ops in order, safe reuse of fbuf
  #pragma unroll
  for (int t = 0; t < 8; t++) {
    int col = 16 * t + l15;
    float bb = bias[col];
    #pragma unroll
    for (int r = 0; r < 4; r++) {
      float x = z1[t][r];
      x = (x > 0.0f) ? x : 0.01f * x;
      fbuf[(4 * q + r) * SBH + col] = x + bb;
    }
  }
  {
    int r_out = lane >> 2, cb = (lane & 3) * 32, mg = m0 + 16 + r_out;
    int ip2 = idx_p[mg], ik2 = idx_k[mg];
    bool dop = (wp[ip2] == mg), dok = (wk[ik2] == mg);
    const float* src = fbuf + r_out * SBH + cb;
    float* dp = out_p + (size_t)ip2 * D + cb;
    float* dk = out_k + (size_t)ik2 * D + cb;
    #pragma unroll
    for (int c = 0; c < 32; c += 4) {
      float4v v = *(const float4v*)(src + c);
      if (dop) *(float4v*)(dp + c) = v;
      if (dok) *(float4v*)(dk + c) = v;
    }
  }
  #undef LDSTAGE
  #undef STSTAGE
}

extern "C" void kernel_launch(void* const* d_in, const int* in_sizes, int n_in,
                              void* d_out, int out_size, void* d_ws, size_t ws_size,
                              hipStream_t stream) {
  const float* h_p      = (const float*)d_in[0];
  const float* h_k      = (const float*)d_in[1];
  const float* h_o      = (const float*)d_in[2];
  const float* weight_o = (const float*)d_in[3];
  const float* weight_p = (const float*)d_in[4];
  const float* lin_W    = (const float*)d_in[5];
  const float* lin_b    = (const float*)d_in[6];
  const float* bias     = (const float*)d_in[7];
  const float* Wq       = (const float*)d_in[8];
  const float* bq       = (const float*)d_in[9];
  const float* Wk       = (const float*)d_in[10];
  const float* bk       = (const float*)d_in[11];
  const float* Wv       = (const float*)d_in[12];
  const float* bv       = (const float*)d_in[13];
  const float* W1       = (const float*)d_in[14];
  const float* b1       = (const float*)d_in[15];
  const float* ln_g     = (const float*)d_in[16];
  const float* ln_b     = (const float*)d_in[17];
  const int*   idx_p    = (const int*)d_in[18];
  const int*   idx_k    = (const int*)d_in[19];
  (void)bk;

  const int ho_rows = in_sizes[2] / D;   // 262144 — NOT NROWS; indices must clamp

  float* out_p = (float*)d_out;
  float* out_k = out_p + (size_t)NROWS * D;

  int* wp = (int*)d_ws;
  int* wk = wp + NROWS;
  short* wbuf = (short*)((char*)d_ws + (size_t)2 * NROWS * 4);   // 160KB of frags
  float* Mbuf = (float*)((char*)wbuf + 81920 * 2);               // 64KB  M = Wq^T Wk
  float* v2   = Mbuf + 128 * 128;                                 // 512B  Wk^T bq

  hipMemsetAsync(wp, 0xFF, (size_t)2 * NROWS * sizeof(int), stream);   // winners = -1

  winners_kernel<<<dim3(MIDX / 256), dim3(256), 0, stream>>>(idx_p, idx_k, wp, wk);
  copyrest_kernel<<<dim3((NROWS * 32 + 255) / 256), dim3(256), 0, stream>>>(
      h_p, h_k, wp, wk, out_p, out_k);
  prep_m_kernel<<<dim3(65), dim3(256), 0, stream>>>(Wq, Wk, bq, Mbuf, v2);
  pack_kernel<<<dim3(160), dim3(64), 0, stream>>>(Mbuf, Wv, W1, lin_W, weight_o, weight_p, wbuf);
  fused_kernel<<<dim3(MIDX / 128), dim3(256), 0, stream>>>(
      h_p, h_k, h_o, ho_rows, idx_p, idx_k, wbuf, v2, bv, b1, lin_b, bias, ln_g, ln_b,
      wp, wk, out_p, out_k);
}